// Round 4
// baseline (16009.480 us; speedup 1.0000x reference)
//
#include <hip/hip_runtime.h>
#include <cmath>

// LIF_complex round 9: arrival-driven consumption -- barrier 1 deleted.
// Round 8 (14.8 ms, 4300 cy/step) audit: active-CU VALU span ~900 cy,
// updater ~300, publish->observe ~700-1000. The unexplained ~1500-2000 cy
// is max-of-128 statistics at bar1: every step waits for the SLOWEST
// publisher before ANY dot starts, serially.
// Round 9: thread (j,k)'s dot needs exactly ONE slot (slot_i = 32j+k/2);
// only the wave-0 update needs all of them (and it already waits at bar2).
//  - relay spread over all 16 waves: wave w relays slots 32j+8i+lane
//    (lanes 0-7, a subset of its own 32-slot need-set), divergent spin,
//    IMMEDIATE tagged store to LDS on observation;
//  - consumers spin locally on their tagged word ((tag16<<16)|bits16) and
//    start select+dot as soon as it lands -> laggard-publisher tail
//    overlaps the ~900 cy dot span instead of preceding it;
//  - bar2 kept (preduce handoff; also makes the single sbits[] tag scheme
//    race-free: step-t relay writes follow bar2(t-1), step-(t-1) consumer
//    reads precede it);
//  - overwrite safety, same induction: b publishes t after bar2(t) <=
//    consumed all sbits@t-1 <= all owners published t-1 <= every owner's
//    waves relay-loaded ALL 128 slots (incl. slot b) at tag t-2. OK.
// Dot, DPP tree, update math, publish order untouched -> bit-identical
// trajectory; absmax must stay exactly 0.001953125.

#define T_STEPS 8192
#define NN      2048
#define NBLK    128
#define NTHR    1024
#define RPB     16
#define DUMP    64
#define NSLOT   128
#define PADU    16   // u64s per slot: one 128 B line per block

typedef unsigned long long u64;

__device__ __forceinline__ float stable_sigmoid(float x) {
    if (x >= 0.0f) {
        return 1.0f / (1.0f + expf(-x));
    } else {
        float e = expf(x);
        return e / (1.0f + e);
    }
}

// acc += dpp_shuffled(acc); masked-out / out-of-bounds lanes add 0.0f.
// Only lane 63's final value is consumed.
#define DPP_ADD(acc, ctrl, rmask)                                         \
    acc += __int_as_float(__builtin_amdgcn_update_dpp(                    \
        0, __float_as_int(acc), ctrl, rmask, 0xF, true));

// Full 64-lane sum (bitwise == xor-butterfly result), answer in lane 63.
#define WAVE_RED(acc)            \
    DPP_ADD(acc, 0x111, 0xF)     \
    DPP_ADD(acc, 0x112, 0xF)     \
    DPP_ADD(acc, 0x114, 0xF)     \
    DPP_ADD(acc, 0x118, 0xF)     \
    DPP_ADD(acc, 0x142, 0xA)     \
    DPP_ADD(acc, 0x143, 0xC)

__global__ __launch_bounds__(NTHR, 2) void lif_kernel(
    const float* __restrict__ x_in,    // [T, N]
    const float* __restrict__ w,       // [N, N]
    const float* __restrict__ v_rest,  // [N]
    const float* __restrict__ tau_m,   // [N]
    const float* __restrict__ tau_g,   // [N]
    const float* __restrict__ pre_cp,  // [1]
    const float* __restrict__ post_cp, // [1]
    const float* __restrict__ v0,      // [N]
    const float* __restrict__ g0,      // [N]
    float* __restrict__ out,           // [2, T, N]
    u64* __restrict__ slots)           // [2, NSLOT, PADU] tagged spike slots
{
    __shared__ unsigned sbits[NSLOT];         // tagged: (tag16<<16)|bits16
    __shared__ float preduce[2][4][RPB];      // double-buffered partials
    __shared__ float vbuf[2][DUMP][RPB];      // double-buffered dump window
    __shared__ float sbuf[2][DUMP][RPB];

    const int tid = threadIdx.x;
    const int b   = blockIdx.x;
    const int wv  = tid >> 6;
    const int i   = wv & 3;            // row group (4 rows)
    const int j   = wv >> 2;           // col group (512 cols)
    const int k   = tid & 63;          // lane

    // ---- w tile into named registers: rows b*16+4i..+3, cols 512j+8k..+7
    const float* wbase = w + (size_t)(b * RPB + 4 * i) * NN + 512 * j;
    const float4* r0 = (const float4*)(wbase);
    const float4* r1 = (const float4*)(wbase + NN);
    const float4* r2 = (const float4*)(wbase + 2 * NN);
    const float4* r3 = (const float4*)(wbase + 3 * NN);
    const float4 w0a = r0[2 * k], w0b = r0[2 * k + 1];
    const float4 w1a = r1[2 * k], w1b = r1[2 * k + 1];
    const float4 w2a = r2[2 * k], w2b = r2[2 * k + 1];
    const float4 w3a = r3[2 * k], w3b = r3[2 * k + 1];

    // ---- this thread's 8 g columns live in registers for the whole run
    const int c0 = 512 * j + 8 * k;    // first owned column
    float4 ga = ((const float4*)(g0 + c0))[0];
    float4 gb = ((const float4*)(g0 + c0))[1];
    const float4 tga = ((const float4*)(tau_g + c0))[0];
    const float4 tgb = ((const float4*)(tau_g + c0))[1];
    const float4 rga = make_float4(1.0f / tga.x, 1.0f / tga.y,
                                   1.0f / tga.z, 1.0f / tga.w);
    const float4 rgb = make_float4(1.0f / tgb.x, 1.0f / tgb.y,
                                   1.0f / tgb.z, 1.0f / tgb.w);
    const int slot_i  = c0 >> 4;       // the ONE slot this thread's dot needs
    const int bitbase = c0 & 15;       // 0 or 8: bit offset in that slot

    // relay assignment: wave w covers slots 32j+8i .. 32j+8i+7 (lanes 0-7),
    // a subset of its own consumer need-set {32j .. 32j+31}
    const int rs = 32 * j + 8 * i + (k & 7);

    const float pre_c  = pre_cp[0];
    const float post_c = post_cp[0];

    // init sbits to a never-matching tag (tags are < 8192 < 0xFFFF);
    // ordered before first use (t=1) by bar2 of step 0
    if (tid < NSLOT) sbits[tid] = 0xFFFF0000u;

    // ---- neuron v-state lives in wave 0, lanes 0..15
    float vr = 0.f, rtm = 0.f, v = 0.f;
    if (tid < RPB) {
        const int n = b * RPB + tid;
        vr  = v_rest[n];
        rtm = 1.0f / tau_m[n];         // exact for tau_m = 4
        v   = v0[n];
    }

    for (int t = 0; t < T_STEPS; ++t) {
        // x prefetch (consumed by wave 0 after bar2)
        float x = 0.0f;
        if (tid < RPB) x = x_in[(size_t)t * NN + b * RPB + tid];

        float4 da = ga, db = gb;
        if (t != 0) {
            // speculative decay: independent of the incoming spike bits.
            // fma(-r,g,g) == g - g/tau (exact for tau_g = 2).
            da.x = fmaf(-rga.x, ga.x, ga.x); da.y = fmaf(-rga.y, ga.y, ga.y);
            da.z = fmaf(-rga.z, ga.z, ga.z); da.w = fmaf(-rga.w, ga.w, ga.w);
            db.x = fmaf(-rgb.x, gb.x, gb.x); db.y = fmaf(-rgb.y, gb.y, gb.y);
            db.z = fmaf(-rgb.z, gb.z, gb.z); db.w = fmaf(-rgb.w, gb.w, gb.w);

            const unsigned want = (unsigned)(t - 1);

            // ---- relay (lanes 0-7): spin on this wave's 8 global slots,
            // store each to LDS IMMEDIATELY on observation
            {
                const u64* sl = slots +
                    ((size_t)((t - 1) & 1) * NSLOT + rs) * PADU;
                bool pending = (k < 8);
                while (__any(pending)) {
                    if (pending) {
                        u64 A = __hip_atomic_load(sl, __ATOMIC_RELAXED,
                                                  __HIP_MEMORY_SCOPE_AGENT);
                        if ((unsigned)(A >> 32) == want) {
                            __hip_atomic_store(
                                &sbits[rs],
                                (want << 16) | ((unsigned)A & 0xFFFFu),
                                __ATOMIC_RELAXED,
                                __HIP_MEMORY_SCOPE_WORKGROUP);
                            pending = false;
                        }
                    }
                    if (__any(pending)) __builtin_amdgcn_s_sleep(1);
                }
            }

            // ---- consume: spin locally on the ONE word this lane needs
            unsigned wval;
            const unsigned wtag = want << 16;
            for (;;) {
                wval = __hip_atomic_load(&sbits[slot_i], __ATOMIC_RELAXED,
                                         __HIP_MEMORY_SCOPE_WORKGROUP);
                if ((wval & 0xFFFF0000u) == wtag) break;  // per-lane exit
                __builtin_amdgcn_s_sleep(1);
            }
            const unsigned bits = (wval & 0xFFFFu) >> bitbase;
            ga.x = (bits &   1u) ? 1.0f : da.x;
            ga.y = (bits &   2u) ? 1.0f : da.y;
            ga.z = (bits &   4u) ? 1.0f : da.z;
            ga.w = (bits &   8u) ? 1.0f : da.w;
            gb.x = (bits &  16u) ? 1.0f : db.x;
            gb.y = (bits &  32u) ? 1.0f : db.y;
            gb.z = (bits &  64u) ? 1.0f : db.z;
            gb.w = (bits & 128u) ? 1.0f : db.w;
        }

        // ---- dot: rows 4i..4i+3 x cols 512j+8k..+7, w and g from registers
        float a0 = 0.f, a1 = 0.f, a2 = 0.f, a3 = 0.f;
#define ROWFMA(acc, wa, wb)                                       \
        acc = fmaf(wa.x, ga.x, acc); acc = fmaf(wa.y, ga.y, acc); \
        acc = fmaf(wa.z, ga.z, acc); acc = fmaf(wa.w, ga.w, acc); \
        acc = fmaf(wb.x, gb.x, acc); acc = fmaf(wb.y, gb.y, acc); \
        acc = fmaf(wb.z, gb.z, acc); acc = fmaf(wb.w, gb.w, acc);
        ROWFMA(a0, w0a, w0b)
        ROWFMA(a1, w1a, w1b)
        ROWFMA(a2, w2a, w2b)
        ROWFMA(a3, w3a, w3b)
#undef ROWFMA
        // 64-lane sum via DPP (VALU pipe only; bitwise == old butterfly),
        // result in lane 63
        WAVE_RED(a0)
        WAVE_RED(a1)
        WAVE_RED(a2)
        WAVE_RED(a3)
        if (k == 63)
            ((float4*)preduce[t & 1])[j * 4 + i] = make_float4(a0, a1, a2, a3);
        __syncthreads();  // bar2: preduce complete; also the step separator
                          // that keeps the single-sbits tag scheme race-free

        // ---- neuron update + spike-bit publish (wave 0, lanes 0..15)
        if (tid < RPB) {
            const float* pr = (const float*)preduce[t & 1];
            float u = (pr[tid] + pr[tid + 16]) + (pr[tid + 32] + pr[tid + 48]);
            float I = post_c * stable_sigmoid(pre_c * (u + x));
            v = v + (vr - v + I) * rtm;
            bool spk = (v >= 30.0f);
            u64 bal = __ballot(spk);   // bits 0..15 = this block's spikes
            if (tid == 0) {
                u64 pk = ((u64)(unsigned)t << 32) | (bal & 0xFFFFull);
                __hip_atomic_store(slots + ((size_t)(t & 1) * NSLOT + b) * PADU,
                                   pk, __ATOMIC_RELAXED,
                                   __HIP_MEMORY_SCOPE_AGENT);
            }
            // keep the expensive soft-sigmoid/LDS writes BELOW the publish
            __builtin_amdgcn_sched_barrier(0);
            float soft = stable_sigmoid(v - 30.0f);   // pre-reset v
            v = spk ? vr : v;
            vbuf[(t >> 6) & 1][t & (DUMP - 1)][tid] = v;
            sbuf[(t >> 6) & 1][t & (DUMP - 1)][tid] = soft;
        }

        // ---- output dump (after the update so it never delays the
        // publish): window closed 64 steps ago, opposite buffer
        if ((t & (DUMP - 1)) == 0 && t != 0) {
            const int bb = ((t >> 6) & 1) ^ 1;
            const int t0 = t - DUMP;
            const int s  = tid >> 4;
            const int rr = tid & 15;
            size_t o = (size_t)(t0 + s) * NN + b * RPB + rr;
            out[o] = vbuf[bb][s][rr];
            out[(size_t)T_STEPS * NN + o] = sbuf[bb][s][rr];
        }
        // no trailing barrier: step-(t+1) sbits writes follow each wave's
        // bar2(t) arrival; preduce alternates parity; vbuf half-buffers
        // alternate every 64 steps; slot overwrite is 2 steps away.
    }

    // ---- final window dump
    __syncthreads();
    {
        const int bb = ((T_STEPS - DUMP) >> 6) & 1;
        const int t0 = T_STEPS - DUMP;
        const int s  = tid >> 4;
        const int rr = tid & 15;
        size_t o = (size_t)(t0 + s) * NN + b * RPB + rr;
        out[o] = vbuf[bb][s][rr];
        out[(size_t)T_STEPS * NN + o] = sbuf[bb][s][rr];
    }
}

extern "C" void kernel_launch(void* const* d_in, const int* in_sizes, int n_in,
                              void* d_out, int out_size, void* d_ws, size_t ws_size,
                              hipStream_t stream) {
    const float* x_in   = (const float*)d_in[0];
    const float* w      = (const float*)d_in[1];
    const float* v_rest = (const float*)d_in[2];
    const float* tau_m  = (const float*)d_in[3];
    const float* tau_g  = (const float*)d_in[4];
    const float* pre_c  = (const float*)d_in[5];
    const float* post_c = (const float*)d_in[6];
    const float* v0     = (const float*)d_in[7];
    const float* g0     = (const float*)d_in[8];
    float* out = (float*)d_out;

    u64* slots = (u64*)d_ws;  // [2, NSLOT, PADU]

    // tag 0xFFFFFFFF never matches any t in [0, 8192)
    hipMemsetAsync(slots, 0xFF, 2 * NSLOT * PADU * sizeof(u64), stream);

    void* args[] = {
        (void*)&x_in, (void*)&w, (void*)&v_rest, (void*)&tau_m, (void*)&tau_g,
        (void*)&pre_c, (void*)&post_c, (void*)&v0, (void*)&g0,
        (void*)&out, (void*)&slots
    };
    hipLaunchCooperativeKernel((void*)lif_kernel, dim3(NBLK), dim3(NTHR),
                               args, 0, stream);
}

// Round 5
// 15097.360 us; speedup vs baseline: 1.0604x; 1.0604x over previous
//
#include <hip/hip_runtime.h>
#include <cmath>

// LIF_complex round 10: round-8 skeleton + phase-staggered dual-cohort poll.
// Round 9 (arrival-driven, bar1 deleted) REGRESSED 14.8->16.0 ms: all 16
// waves spinning stole issue slots (VALUBusy 19.5->21.8 with longer dur),
// and the "statistical laggard tail" premise was wrong -- the 128 blocks
// run lockstep, the hop is deterministic. Reverted to round 8.
// Round-8 budget audit (4300 cy/step): compute ~650, update ~300,
// barriers/relay ~250 -> ~3000 cy is the agent-scope (MALL) fabric hop,
// i.e. L ~ 1500-2000 cy cross-XCD load latency, paid as in-flight miss +
// full-period retry overshoot (~L/2) + hit. The addressable slice is the
// retry quantization:
//  - waves 0-1 poll slots (wv<<6)|k as in round 8 (cohort A);
//  - waves 2-3 poll the SAME slots phase-shifted by s_sleep(6) (~384 cy)
//    before their first load (cohort B) -> expected overshoot ~L/4 instead
//    of ~L/2. First observer stores to sbits (relaxed atomic; both write
//    identical values -- benign). Waves 2-3 previously slept at bar1 during
//    this exact window: zero new issue contention (round-9 lesson).
//  - cohort B also covers wave 0's post-publish straggle (soft sigmoid +
//    vbuf writes delay its next-step poll).
// Also: branch-free bit-exact stable_sigmoid (E=expf(-|x|); (x>=0?1:E)/(1+E)
// -- identical ops/order per branch) shortens the 16-lane updater chain.
// Everything else is byte-for-byte round 8: dot, DPP tree (bitwise == the
// old xor butterfly), publish order, tag protocol & overwrite-safety
// induction. absmax must stay exactly 0.001953125 (bit-exactness canary).

#define T_STEPS 8192
#define NN      2048
#define NBLK    128
#define NTHR    1024
#define RPB     16
#define DUMP    64
#define NSLOT   128
#define PADU    16   // u64s per slot: one 128 B line per block

typedef unsigned long long u64;

__device__ __forceinline__ float stable_sigmoid(float x) {
    // Bit-exact, branch-free form of:
    //   x>=0 ? 1/(1+expf(-x)) : expf(x)/(1+expf(x))
    // (-x == -|x| exactly for x>=0; x == -|x| for x<0; same op order.)
    float E   = expf(-fabsf(x));
    float den = 1.0f + E;
    float num = (x >= 0.0f) ? 1.0f : E;
    return num / den;
}

// acc += dpp_shuffled(acc); masked-out / out-of-bounds lanes add 0.0f.
// Only lane 63's final value is consumed.
#define DPP_ADD(acc, ctrl, rmask)                                         \
    acc += __int_as_float(__builtin_amdgcn_update_dpp(                    \
        0, __float_as_int(acc), ctrl, rmask, 0xF, true));

// Full 64-lane sum (bitwise == xor-butterfly result), answer in lane 63.
#define WAVE_RED(acc)            \
    DPP_ADD(acc, 0x111, 0xF)     \
    DPP_ADD(acc, 0x112, 0xF)     \
    DPP_ADD(acc, 0x114, 0xF)     \
    DPP_ADD(acc, 0x118, 0xF)     \
    DPP_ADD(acc, 0x142, 0xA)     \
    DPP_ADD(acc, 0x143, 0xC)

__global__ __launch_bounds__(NTHR, 2) void lif_kernel(
    const float* __restrict__ x_in,    // [T, N]
    const float* __restrict__ w,       // [N, N]
    const float* __restrict__ v_rest,  // [N]
    const float* __restrict__ tau_m,   // [N]
    const float* __restrict__ tau_g,   // [N]
    const float* __restrict__ pre_cp,  // [1]
    const float* __restrict__ post_cp, // [1]
    const float* __restrict__ v0,      // [N]
    const float* __restrict__ g0,      // [N]
    float* __restrict__ out,           // [2, T, N]
    u64* __restrict__ slots)           // [2, NSLOT, PADU] tagged spike slots
{
    __shared__ unsigned sbits[NSLOT];         // relayed spike bits, step t-1
    __shared__ float preduce[2][4][RPB];      // double-buffered partials
    __shared__ float vbuf[2][DUMP][RPB];      // double-buffered dump window
    __shared__ float sbuf[2][DUMP][RPB];

    const int tid = threadIdx.x;
    const int b   = blockIdx.x;
    const int wv  = tid >> 6;
    const int i   = wv & 3;            // row group (4 rows)
    const int j   = wv >> 2;           // col group (512 cols)
    const int k   = tid & 63;          // lane

    // ---- w tile into named registers: rows b*16+4i..+3, cols 512j+8k..+7
    const float* wbase = w + (size_t)(b * RPB + 4 * i) * NN + 512 * j;
    const float4* r0 = (const float4*)(wbase);
    const float4* r1 = (const float4*)(wbase + NN);
    const float4* r2 = (const float4*)(wbase + 2 * NN);
    const float4* r3 = (const float4*)(wbase + 3 * NN);
    const float4 w0a = r0[2 * k], w0b = r0[2 * k + 1];
    const float4 w1a = r1[2 * k], w1b = r1[2 * k + 1];
    const float4 w2a = r2[2 * k], w2b = r2[2 * k + 1];
    const float4 w3a = r3[2 * k], w3b = r3[2 * k + 1];

    // ---- this thread's 8 g columns live in registers for the whole run
    const int c0 = 512 * j + 8 * k;    // first owned column
    float4 ga = ((const float4*)(g0 + c0))[0];
    float4 gb = ((const float4*)(g0 + c0))[1];
    const float4 tga = ((const float4*)(tau_g + c0))[0];
    const float4 tgb = ((const float4*)(tau_g + c0))[1];
    const float4 rga = make_float4(1.0f / tga.x, 1.0f / tga.y,
                                   1.0f / tga.z, 1.0f / tga.w);
    const float4 rgb = make_float4(1.0f / tgb.x, 1.0f / tgb.y,
                                   1.0f / tgb.z, 1.0f / tgb.w);
    const int slot_i  = c0 >> 4;       // owning block of these 8 cols
    const int bitbase = c0 & 15;       // 0 or 8: bit offset in that slot

    const float pre_c  = pre_cp[0];
    const float post_c = post_cp[0];

    // ---- neuron v-state lives in wave 0, lanes 0..15
    float vr = 0.f, rtm = 0.f, v = 0.f;
    if (tid < RPB) {
        const int n = b * RPB + tid;
        vr  = v_rest[n];
        rtm = 1.0f / tau_m[n];         // exact for tau_m = 4
        v   = v0[n];
    }

    for (int t = 0; t < T_STEPS; ++t) {
        // x prefetch (consumed by wave 0 after barrier 2)
        float x = 0.0f;
        if (tid < RPB) x = x_in[(size_t)t * NN + b * RPB + tid];

        float4 da = ga, db = gb;
        if (t != 0) {
            // speculative decay: independent of the incoming spike bits.
            // fma(-r,g,g) == g - g/tau (exact for tau_g = 2).
            da.x = fmaf(-rga.x, ga.x, ga.x); da.y = fmaf(-rga.y, ga.y, ga.y);
            da.z = fmaf(-rga.z, ga.z, ga.z); da.w = fmaf(-rga.w, ga.w, ga.w);
            db.x = fmaf(-rgb.x, gb.x, gb.x); db.y = fmaf(-rgb.y, gb.y, gb.y);
            db.z = fmaf(-rgb.z, gb.z, gb.z); db.w = fmaf(-rgb.w, gb.w, gb.w);

            // ---- poll spikes(t-1): cohort A = waves 0-1 (slots (wv&1)<<6|k,
            // immediate), cohort B = waves 2-3 (same slots, phase-shifted by
            // ~384 cy pre-sleep). First observer relays to sbits; both write
            // identical values. Each of the 128 lines is read once per
            // cohort per poll round.
            if (wv < 4) {
                const int s = ((wv & 1) << 6) | k;
                const u64* sl = slots +
                    ((size_t)((t - 1) & 1) * NSLOT + s) * PADU;
                const unsigned want = (unsigned)(t - 1);
                if (wv >= 2) __builtin_amdgcn_s_sleep(6);  // phase offset
                u64 A = __hip_atomic_load(sl, __ATOMIC_RELAXED,
                                          __HIP_MEMORY_SCOPE_AGENT);
                while ((unsigned)(A >> 32) != want) {
                    __builtin_amdgcn_s_sleep(1);
                    A = __hip_atomic_load(sl, __ATOMIC_RELAXED,
                                          __HIP_MEMORY_SCOPE_AGENT);
                }
                __hip_atomic_store(&sbits[s], (unsigned)A,
                                   __ATOMIC_RELAXED,
                                   __HIP_MEMORY_SCOPE_WORKGROUP);
            }
        }
        __syncthreads();  // barrier 1: sbits complete; certifies all 128
                          // slots observed at tag t-1 block-wide

        if (t != 0) {
            const unsigned bits = sbits[slot_i] >> bitbase;  // broadcast read
            ga.x = (bits &   1u) ? 1.0f : da.x;
            ga.y = (bits &   2u) ? 1.0f : da.y;
            ga.z = (bits &   4u) ? 1.0f : da.z;
            ga.w = (bits &   8u) ? 1.0f : da.w;
            gb.x = (bits &  16u) ? 1.0f : db.x;
            gb.y = (bits &  32u) ? 1.0f : db.y;
            gb.z = (bits &  64u) ? 1.0f : db.z;
            gb.w = (bits & 128u) ? 1.0f : db.w;
        }

        // ---- dot: rows 4i..4i+3 x cols 512j+8k..+7, w and g from registers
        float a0 = 0.f, a1 = 0.f, a2 = 0.f, a3 = 0.f;
#define ROWFMA(acc, wa, wb)                                       \
        acc = fmaf(wa.x, ga.x, acc); acc = fmaf(wa.y, ga.y, acc); \
        acc = fmaf(wa.z, ga.z, acc); acc = fmaf(wa.w, ga.w, acc); \
        acc = fmaf(wb.x, gb.x, acc); acc = fmaf(wb.y, gb.y, acc); \
        acc = fmaf(wb.z, gb.z, acc); acc = fmaf(wb.w, gb.w, acc);
        ROWFMA(a0, w0a, w0b)
        ROWFMA(a1, w1a, w1b)
        ROWFMA(a2, w2a, w2b)
        ROWFMA(a3, w3a, w3b)
#undef ROWFMA
        // 64-lane sum via DPP (VALU pipe only; bitwise == old butterfly),
        // result in lane 63
        WAVE_RED(a0)
        WAVE_RED(a1)
        WAVE_RED(a2)
        WAVE_RED(a3)
        if (k == 63)
            ((float4*)preduce[t & 1])[j * 4 + i] = make_float4(a0, a1, a2, a3);
        __syncthreads();  // barrier 2: preduce complete

        // ---- neuron update + spike-bit publish (wave 0, lanes 0..15)
        if (tid < RPB) {
            const float* pr = (const float*)preduce[t & 1];
            float u = (pr[tid] + pr[tid + 16]) + (pr[tid + 32] + pr[tid + 48]);
            float I = post_c * stable_sigmoid(pre_c * (u + x));
            v = v + (vr - v + I) * rtm;
            bool spk = (v >= 30.0f);
            u64 bal = __ballot(spk);   // bits 0..15 = this block's spikes
            if (tid == 0) {
                u64 pk = ((u64)(unsigned)t << 32) | (bal & 0xFFFFull);
                __hip_atomic_store(slots + ((size_t)(t & 1) * NSLOT + b) * PADU,
                                   pk, __ATOMIC_RELAXED,
                                   __HIP_MEMORY_SCOPE_AGENT);
            }
            // keep the expensive soft-sigmoid/LDS writes BELOW the publish
            __builtin_amdgcn_sched_barrier(0);
            float soft = stable_sigmoid(v - 30.0f);   // pre-reset v
            v = spk ? vr : v;
            vbuf[(t >> 6) & 1][t & (DUMP - 1)][tid] = v;
            sbuf[(t >> 6) & 1][t & (DUMP - 1)][tid] = soft;
        }

        // ---- output dump (after the update so it never delays the
        // publish): window closed 64 steps ago, opposite buffer
        if ((t & (DUMP - 1)) == 0 && t != 0) {
            const int bb = ((t >> 6) & 1) ^ 1;
            const int t0 = t - DUMP;
            const int s  = tid >> 4;
            const int rr = tid & 15;
            size_t o = (size_t)(t0 + s) * NN + b * RPB + rr;
            out[o] = vbuf[bb][s][rr];
            out[(size_t)T_STEPS * NN + o] = sbuf[bb][s][rr];
        }
        // no trailing barrier: next sbits write is by waves 0-3 after THEIR
        // barrier-2 arrival; preduce alternates parity; vbuf half-buffers
        // alternate every 64 steps; slot overwrite is 2 steps away.
    }

    // ---- final window dump
    __syncthreads();
    {
        const int bb = ((T_STEPS - DUMP) >> 6) & 1;
        const int t0 = T_STEPS - DUMP;
        const int s  = tid >> 4;
        const int rr = tid & 15;
        size_t o = (size_t)(t0 + s) * NN + b * RPB + rr;
        out[o] = vbuf[bb][s][rr];
        out[(size_t)T_STEPS * NN + o] = sbuf[bb][s][rr];
    }
}

extern "C" void kernel_launch(void* const* d_in, const int* in_sizes, int n_in,
                              void* d_out, int out_size, void* d_ws, size_t ws_size,
                              hipStream_t stream) {
    const float* x_in   = (const float*)d_in[0];
    const float* w      = (const float*)d_in[1];
    const float* v_rest = (const float*)d_in[2];
    const float* tau_m  = (const float*)d_in[3];
    const float* tau_g  = (const float*)d_in[4];
    const float* pre_c  = (const float*)d_in[5];
    const float* post_c = (const float*)d_in[6];
    const float* v0     = (const float*)d_in[7];
    const float* g0     = (const float*)d_in[8];
    float* out = (float*)d_out;

    u64* slots = (u64*)d_ws;  // [2, NSLOT, PADU]

    // tag 0xFFFFFFFF never matches any t in [0, 8192)
    hipMemsetAsync(slots, 0xFF, 2 * NSLOT * PADU * sizeof(u64), stream);

    void* args[] = {
        (void*)&x_in, (void*)&w, (void*)&v_rest, (void*)&tau_m, (void*)&tau_g,
        (void*)&pre_c, (void*)&post_c, (void*)&v0, (void*)&g0,
        (void*)&out, (void*)&slots
    };
    hipLaunchCooperativeKernel((void*)lif_kernel, dim3(NBLK), dim3(NTHR),
                               args, 0, stream);
}